// Round 4
// baseline (424.884 us; speedup 1.0000x reference)
//
#include <hip/hip_runtime.h>
#include <math.h>

constexpr int B = 2, A = 900, ED = 256, NG = 8, NCAM = 6, NL = 4, NP = 7;
constexpr int NJ = NG * NCAM * NL * NP;   // 1344
constexpr int NBA = B * A;                // 1800
constexpr int NE = NCAM * NL * NP;        // 168 point-level entries
constexpr int LDST = 260;                 // LDS row stride (16B aligned, conflict-free)

__constant__ float FIXS[NP][3] = {
  {0.f,0.f,0.f},{0.45f,0.f,0.f},{-0.45f,0.f,0.f},
  {0.f,0.45f,0.f},{0.f,-0.45f,0.f},{0.f,0.f,0.45f},{0.f,0.f,-0.45f}};

__constant__ int cH[NL]  = {64,32,16,8};
__constant__ int cW[NL]  = {176,88,44,22};
__constant__ int cHW[NL] = {11264,2816,704,176};
// float offsets of each level inside the channel-last transposed buffer
__constant__ long long cLOFF[NL] = {0LL, 34603008LL, 43253760LL, 45416448LL};

// ---- channel-last transpose, all levels in one launch ----
// in: [bc][256][HW] -> tfeat: [lvl][bc][HW][256]
// tile: 256 ch x 32 px. Reads: thread=channel, float4 along px (128B/row).
// Writes: one wave per output row: 64 lanes x float4 = 1KB coalesced.
__global__ __launch_bounds__(256) void k_tr_cl(
    const float* __restrict__ f0, const float* __restrict__ f1,
    const float* __restrict__ f2, const float* __restrict__ f3,
    float* __restrict__ tfeat)
{
  __shared__ float tile[32 * LDST];
  const int bc = blockIdx.y;
  const int bx = blockIdx.x;
  int lvl, t0;
  if      (bx < 352) { lvl = 0; t0 = 0; }
  else if (bx < 440) { lvl = 1; t0 = 352; }
  else if (bx < 462) { lvl = 2; t0 = 440; }
  else               { lvl = 3; t0 = 462; }
  const int HW  = cHW[lvl];
  const int px0 = (bx - t0) * 32;
  const float* in = ((lvl==0)?f0:(lvl==1)?f1:(lvl==2)?f2:f3)
                    + (size_t)bc * ED * HW + px0;
  float* outp = tfeat + cLOFF[lvl] + ((size_t)bc * HW + px0) * ED;
  const int t = threadIdx.x;
  const int npx = min(32, HW - px0);   // 32, or 16 on level-3 tail tile

#pragma unroll
  for (int j = 0; j < 8; ++j) {
    const int px = 4 * j;
    if (px < npx) {
      const float4 v = *(const float4*)(in + (size_t)t * HW + px);
      tile[(px+0)*LDST + t] = v.x;
      tile[(px+1)*LDST + t] = v.y;
      tile[(px+2)*LDST + t] = v.z;
      tile[(px+3)*LDST + t] = v.w;
    }
  }
  __syncthreads();
  const int wv = t >> 6, l = t & 63;
  for (int px = wv; px < npx; px += 4) {
    const float4 v = *(const float4*)&tile[px*LDST + 4*l];
    *(float4*)(outp + (size_t)px * ED + 4*l) = v;
  }
}

// ---------------- generic 2D transpose (w_fc only): in[R,C] -> out[C,R] ----
__global__ __launch_bounds__(256) void k_tr(const float* __restrict__ in,
                                            float* __restrict__ out, int R, int C)
{
  __shared__ float tile[32][33];
  const int r0 = blockIdx.y * 32, c0 = blockIdx.x * 32;
  const int tx = threadIdx.x, ty = threadIdx.y;  // (32,8)
#pragma unroll
  for (int kk = 0; kk < 4; ++kk) {
    const int r = r0 + ty + kk*8, c = c0 + tx;
    if (r < R && c < C) tile[ty + kk*8][tx] = in[(size_t)r*C + c];
  }
  __syncthreads();
#pragma unroll
  for (int kk = 0; kk < 4; ++kk) {
    const int c = c0 + ty + kk*8, r = r0 + tx;
    if (r < R && c < C) out[(size_t)c*R + r] = tile[tx][ty + kk*8];
  }
}

// ------- FC: wraw[1800,1344] = (inst+emb) @ wt + b_fc, wt = w_fc^T [256,1344] -------
__global__ __launch_bounds__(192) void k_fc(const float* __restrict__ inst,
    const float* __restrict__ emb, const float* __restrict__ wt,
    const float* __restrict__ b_fc, float* __restrict__ wraw)
{
  __shared__ float fsh[8][ED];
  const int a0 = blockIdx.x * 8;
  const int j  = blockIdx.y * 192 + threadIdx.x;
  const int t  = threadIdx.x;

  for (int i = t; i < 8 * ED; i += 192) {
    const int a = i >> 8, k = i & 255;
    const size_t idx = (size_t)(a0 + a) * ED + k;
    fsh[a][k] = inst[idx] + emb[idx];
  }
  __syncthreads();

  float acc[8] = {0.f,0.f,0.f,0.f,0.f,0.f,0.f,0.f};
  for (int k = 0; k < ED; k += 4) {
    float w0 = wt[(size_t)(k+0)*NJ + j];
    float w1 = wt[(size_t)(k+1)*NJ + j];
    float w2 = wt[(size_t)(k+2)*NJ + j];
    float w3 = wt[(size_t)(k+3)*NJ + j];
#pragma unroll
    for (int a = 0; a < 8; ++a)
      acc[a] += w0*fsh[a][k] + w1*fsh[a][k+1] + w2*fsh[a][k+2] + w3*fsh[a][k+3];
  }
  const float bj = b_fc[j];
#pragma unroll
  for (int a = 0; a < 8; ++a)
    wraw[(size_t)(a0+a)*NJ + j] = acc[a] + bj;
}

// ------- fused: softmax + projection + compacted channel-last gather ----
__global__ __launch_bounds__(256) void k_sample_cl(
    const float* __restrict__ anchor, const float* __restrict__ proj,
    const float* __restrict__ wh, const float* __restrict__ wraw,
    const float* __restrict__ tfeat, float* __restrict__ fused)
{
  __shared__ float wsh[NJ];            // [g][e] layout: g*NE+e (conflict-free)
  __shared__ float gridsh[NCAM][NP][2];
  __shared__ const float* cbase[NE];   // tap (0,0) base (channel 0)
  __shared__ float4 cwt[NE];
  __shared__ int4   cmeta[NE];         // x=rowoff(W*ED), y=flags, z=entry idx
  __shared__ int wcnt[4];

  const int ba = blockIdx.x;
  const int b  = ba / A;
  const int t  = threadIdx.x;

  for (int j = t; j < NJ; j += 256)
    wsh[(j & 7) * NE + (j >> 3)] = wraw[(size_t)ba*NJ + j];

  if (t < NCAM*NP) {
    const int c = t / NP, p = t % NP;
    const float* an = anchor + (size_t)ba * 8;
    const float sx = expf(an[3]), sy = expf(an[4]), sz = expf(an[5]);
    const float sn = an[6], cs = an[7];
    const float kx = FIXS[p][0]*sx, ky = FIXS[p][1]*sy, kz = FIXS[p][2]*sz;
    const float px = cs*kx - sn*ky + an[0];
    const float py = sn*kx + cs*ky + an[1];
    const float pz = kz + an[2];
    const float* P = proj + ((size_t)(b*NCAM + c))*16;
    const float X = P[0]*px + P[1]*py + P[2]*pz  + P[3];
    const float Y = P[4]*px + P[5]*py + P[6]*pz  + P[7];
    const float Z = P[8]*px + P[9]*py + P[10]*pz + P[11];
    const float zc  = fmaxf(Z, 1e-5f);
    const float whx = fmaxf(wh[(b*NCAM+c)*2+0], 1e-5f);
    const float why = fmaxf(wh[(b*NCAM+c)*2+1], 1e-5f);
    gridsh[c][p][0] = (X/zc/whx)*2.f - 1.f;
    gridsh[c][p][1] = (Y/zc/why)*2.f - 1.f;
  }
  __syncthreads();

  bool valid = false;
  int fl = 0, rowoff = 0;
  float wx1 = 0.f, wy1 = 0.f;
  const float* bptr = nullptr;
  if (t < NE) {
    const int c = t / (NL*NP); const int r = t % (NL*NP);
    const int l = r / NP, p = r % NP;
    const int Wl = cW[l], Hl = cH[l], HWl = cHW[l];
    const float gx = (gridsh[c][p][0] + 1.f) * (Wl * 0.5f) - 0.5f;
    const float gy = (gridsh[c][p][1] + 1.f) * (Hl * 0.5f) - 0.5f;
    const float x0f = floorf(gx), y0f = floorf(gy);
    const bool vx0 = (x0f >=  0.f) & (x0f <= (float)(Wl-1));
    const bool vx1 = (x0f >= -1.f) & (x0f <= (float)(Wl-2));
    const bool vy0 = (y0f >=  0.f) & (y0f <= (float)(Hl-1));
    const bool vy1 = (y0f >= -1.f) & (y0f <= (float)(Hl-2));
    fl = ((vx0&&vy0)?1:0) | ((vx1&&vy0)?2:0) | ((vx0&&vy1)?4:0) | ((vx1&&vy1)?8:0);
    if (fl) {
      wx1 = gx - x0f; wy1 = gy - y0f;
      const int x0 = (int)x0f, y0 = (int)y0f;
      bptr = tfeat + cLOFF[l]
           + ((size_t)(b*NCAM + c) * HWl + (long long)(y0*Wl + x0)) * ED;
      rowoff = Wl * ED;
      valid = true;
    }
  }

  const unsigned long long mask = __ballot(valid);
  const int lane = t & 63, wv = t >> 6;
  if (lane == 0) wcnt[wv] = __popcll(mask);
  __syncthreads();
  int off = 0, nv = 0;
#pragma unroll
  for (int i = 0; i < 4; ++i) { if (i < wv) off += wcnt[i]; nv += wcnt[i]; }
  if (valid) {
    const int pos = off + __popcll(mask & ((1ull << lane) - 1ull));
    cbase[pos] = bptr;
    cwt[pos]   = make_float4((1.f-wx1)*(1.f-wy1), wx1*(1.f-wy1),
                             (1.f-wx1)*wy1,       wx1*wy1);
    cmeta[pos] = make_int4(rowoff, fl, t, 0);
  }

  // group softmax: 8 groups x 32 lanes, contiguous-e layout (no bank conflicts)
  {
    const int g = t >> 5, ln = t & 31;
    float* wg = wsh + g * NE;
    float m = -3.4e38f;
    for (int i = ln; i < NE; i += 32) m = fmaxf(m, wg[i]);
#pragma unroll
    for (int mk = 16; mk >= 1; mk >>= 1) m = fmaxf(m, __shfl_xor(m, mk));
    float s = 0.f;
    for (int i = ln; i < NE; i += 32) {
      const float e = expf(wg[i] - m);
      wg[i] = e;
      s += e;
    }
#pragma unroll
    for (int mk = 16; mk >= 1; mk >>= 1) s += __shfl_xor(s, mk);
    const float inv = 1.f / s;
    for (int i = ln; i < NE; i += 32) wg[i] *= inv;
  }
  __syncthreads();

  float acc = 0.f;
  const int g = t >> 5;
  for (int i = 0; i < nv; ++i) {
    const float* pb = cbase[i] + t;
    const float4 w4 = cwt[i];
    const int4 m = cmeta[i];
    const float aw = wsh[g*NE + m.z];
    const int ro = m.x, f = m.y;
    float sv = 0.f;
    if (f == 15) {
      sv = w4.x*pb[0] + w4.y*pb[ED] + w4.z*pb[ro] + w4.w*pb[ro+ED];
    } else {
      if (f & 1) sv += w4.x*pb[0];
      if (f & 2) sv += w4.y*pb[ED];
      if (f & 4) sv += w4.z*pb[ro];
      if (f & 8) sv += w4.w*pb[ro+ED];
    }
    acc += aw * sv;
  }
  fused[(size_t)ba*ED + t] = acc;
}

// ------- fallback: native-layout gather (used only if ws too small) ----
__global__ __launch_bounds__(256) void k_sample_nat(
    const float* __restrict__ anchor, const float* __restrict__ proj,
    const float* __restrict__ wh, const float* __restrict__ wraw,
    const float* __restrict__ f0, const float* __restrict__ f1,
    const float* __restrict__ f2, const float* __restrict__ f3,
    float* __restrict__ fused)
{
  __shared__ float wsh[NJ];
  __shared__ float gridsh[NCAM][NP][2];
  const int ba = blockIdx.x;
  const int b  = ba / A;
  const int t  = threadIdx.x;
  for (int j = t; j < NJ; j += 256)
    wsh[(j & 7) * NE + (j >> 3)] = wraw[(size_t)ba*NJ + j];
  if (t < NCAM*NP) {
    const int c = t / NP, p = t % NP;
    const float* an = anchor + (size_t)ba * 8;
    const float sx = expf(an[3]), sy = expf(an[4]), sz = expf(an[5]);
    const float sn = an[6], cs = an[7];
    const float kx = FIXS[p][0]*sx, ky = FIXS[p][1]*sy, kz = FIXS[p][2]*sz;
    const float px = cs*kx - sn*ky + an[0];
    const float py = sn*kx + cs*ky + an[1];
    const float pz = kz + an[2];
    const float* P = proj + ((size_t)(b*NCAM + c))*16;
    const float X = P[0]*px + P[1]*py + P[2]*pz  + P[3];
    const float Y = P[4]*px + P[5]*py + P[6]*pz  + P[7];
    const float Z = P[8]*px + P[9]*py + P[10]*pz + P[11];
    const float zc  = fmaxf(Z, 1e-5f);
    const float whx = fmaxf(wh[(b*NCAM+c)*2+0], 1e-5f);
    const float why = fmaxf(wh[(b*NCAM+c)*2+1], 1e-5f);
    gridsh[c][p][0] = (X/zc/whx)*2.f - 1.f;
    gridsh[c][p][1] = (Y/zc/why)*2.f - 1.f;
  }
  __syncthreads();
  {
    const int g = t >> 5, ln = t & 31;
    float* wg = wsh + g * NE;
    float m = -3.4e38f;
    for (int i = ln; i < NE; i += 32) m = fmaxf(m, wg[i]);
#pragma unroll
    for (int mk = 16; mk >= 1; mk >>= 1) m = fmaxf(m, __shfl_xor(m, mk));
    float s = 0.f;
    for (int i = ln; i < NE; i += 32) { const float e = expf(wg[i]-m); wg[i]=e; s+=e; }
#pragma unroll
    for (int mk = 16; mk >= 1; mk >>= 1) s += __shfl_xor(s, mk);
    const float inv = 1.f / s;
    for (int i = ln; i < NE; i += 32) wg[i] *= inv;
  }
  __syncthreads();
  float acc = 0.f;
  const int g = t >> 5;
  for (int e = 0; e < NE; ++e) {
    const int c = e / (NL*NP);
    const int l = (e / NP) % NL;
    const int p = e % NP;
    const int Wl = cW[l], Hl = cH[l], HWl = cHW[l];
    const float gx = (gridsh[c][p][0] + 1.f) * (Wl * 0.5f) - 0.5f;
    const float gy = (gridsh[c][p][1] + 1.f) * (Hl * 0.5f) - 0.5f;
    const float x0f = floorf(gx), y0f = floorf(gy);
    const bool vx0 = (x0f >=  0.f) & (x0f <= (float)(Wl-1));
    const bool vx1 = (x0f >= -1.f) & (x0f <= (float)(Wl-2));
    const bool vy0 = (y0f >=  0.f) & (y0f <= (float)(Hl-1));
    const bool vy1 = (y0f >= -1.f) & (y0f <= (float)(Hl-2));
    const int fl = ((vx0&&vy0)?1:0)|((vx1&&vy0)?2:0)|((vx0&&vy1)?4:0)|((vx1&&vy1)?8:0);
    if (!fl) continue;
    const float wx1 = gx - x0f, wy1 = gy - y0f;
    const int x0 = (int)x0f, y0 = (int)y0f;
    const float* fp = (l==0)?f0:(l==1)?f1:(l==2)?f2:f3;
    const float* pb = fp + ((size_t)(b*NCAM+c)*ED + t)*HWl + (long long)(y0*Wl+x0);
    float sv = 0.f;
    if (fl & 1) sv += (1.f-wx1)*(1.f-wy1)*pb[0];
    if (fl & 2) sv += wx1*(1.f-wy1)*pb[1];
    if (fl & 4) sv += (1.f-wx1)*wy1*pb[Wl];
    if (fl & 8) sv += wx1*wy1*pb[Wl+1];
    acc += wsh[g*NE + e] * sv;
  }
  fused[(size_t)ba*ED + t] = acc;
}

// ---------------- out = fused @ w_out^T + b_out ----------------
__global__ __launch_bounds__(256) void k_out(const float* __restrict__ fused,
    const float* __restrict__ w_out, const float* __restrict__ b_out,
    float* __restrict__ out)
{
  __shared__ float fsh[8][ED];
  const int a0 = blockIdx.x * 8;
  const int t = threadIdx.x;
#pragma unroll
  for (int k = 0; k < 8; ++k) fsh[k][t] = fused[(size_t)(a0+k)*ED + t];
  __syncthreads();
  float acc[8] = {0.f,0.f,0.f,0.f,0.f,0.f,0.f,0.f};
  for (int i = 0; i < ED; i += 4) {
    const float4 w4 = *(const float4*)&w_out[(size_t)t*ED + i];
#pragma unroll
    for (int k = 0; k < 8; ++k) {
      const float4 fv = *(const float4*)&fsh[k][i];
      acc[k] += w4.x*fv.x + w4.y*fv.y + w4.z*fv.z + w4.w*fv.w;
    }
  }
  const float bo = b_out[t];
#pragma unroll
  for (int k = 0; k < 8; ++k) out[(size_t)(a0+k)*ED + t] = acc[k] + bo;
}

extern "C" void kernel_launch(void* const* d_in, const int* in_sizes, int n_in,
                              void* d_out, int out_size, void* d_ws, size_t ws_size,
                              hipStream_t stream) {
  const float* inst   = (const float*)d_in[0];
  const float* anchor = (const float*)d_in[1];
  const float* emb    = (const float*)d_in[2];
  const float* f0 = (const float*)d_in[3];
  const float* f1 = (const float*)d_in[4];
  const float* f2 = (const float*)d_in[5];
  const float* f3 = (const float*)d_in[6];
  const float* proj  = (const float*)d_in[7];
  const float* wh    = (const float*)d_in[8];
  const float* w_fc  = (const float*)d_in[9];
  const float* b_fc  = (const float*)d_in[10];
  const float* w_out = (const float*)d_in[11];
  const float* b_out = (const float*)d_in[12];
  float* out = (float*)d_out;
  float* ws  = (float*)d_ws;

  const size_t TFEAT = 45957120ULL;
  const size_t WRAW  = (size_t)NBA * NJ;
  const size_t FUSED = (size_t)NBA * ED;
  const size_t WT    = (size_t)ED * NJ;
  const bool tr = ws_size >= (TFEAT + WRAW + FUSED + WT) * sizeof(float);

  float* tfeat  = ws;
  float* wraw   = tr ? (ws + TFEAT) : ws;
  float* fusedp = wraw + WRAW;
  float* wt     = fusedp + FUSED;

  // w_fc [1344,256] -> wt [256,1344]
  k_tr<<<dim3(ED/32, NJ/32, 1), dim3(32,8), 0, stream>>>(w_fc, wt, NJ, ED);

  if (tr)
    k_tr_cl<<<dim3(468, B*NCAM), 256, 0, stream>>>(f0, f1, f2, f3, tfeat);

  k_fc<<<dim3(NBA / 8, 7), 192, 0, stream>>>(inst, emb, wt, b_fc, wraw);

  if (tr)
    k_sample_cl<<<NBA, 256, 0, stream>>>(anchor, proj, wh, wraw, tfeat, fusedp);
  else
    k_sample_nat<<<NBA, 256, 0, stream>>>(anchor, proj, wh, wraw,
                                          f0, f1, f2, f3, fusedp);

  k_out<<<NBA / 8, 256, 0, stream>>>(fusedp, w_out, b_out, out);
}

// Round 5
// 380.788 us; speedup vs baseline: 1.1158x; 1.1158x over previous
//
#include <hip/hip_runtime.h>
#include <math.h>

constexpr int B = 2, A = 900, ED = 256, NG = 8, NCAM = 6, NL = 4, NP = 7;
constexpr int NJ = NG * NCAM * NL * NP;   // 1344
constexpr int NBA = B * A;                // 1800
constexpr int NE = NCAM * NL * NP;        // 168 point-level entries
constexpr int LDST = 260;                 // LDS row stride (16B aligned)

__constant__ float FIXS[NP][3] = {
  {0.f,0.f,0.f},{0.45f,0.f,0.f},{-0.45f,0.f,0.f},
  {0.f,0.45f,0.f},{0.f,-0.45f,0.f},{0.f,0.f,0.45f},{0.f,0.f,-0.45f}};

__constant__ int cH[NL]  = {64,32,16,8};
__constant__ int cW[NL]  = {176,88,44,22};
__constant__ int cHW[NL] = {11264,2816,704,176};
// float offsets of levels 1..3 inside tfeat (level 0 stays native)
__constant__ long long cLOFF[NL] = {0LL, 0LL, 8650752LL, 10813440LL};

// ---- channel-last transpose, levels 1-3 only ----
// in: [bc][256][HW] -> tfeat: [lvl][bc][HW][256]
__global__ __launch_bounds__(256) void k_tr_cl(
    const float* __restrict__ f1, const float* __restrict__ f2,
    const float* __restrict__ f3, float* __restrict__ tfeat)
{
  __shared__ float tile[32 * LDST];
  const int bc = blockIdx.y;
  const int bx = blockIdx.x;
  int lvl, t0;
  if      (bx < 88)  { lvl = 1; t0 = 0; }
  else if (bx < 110) { lvl = 2; t0 = 88; }
  else               { lvl = 3; t0 = 110; }
  const int HW  = cHW[lvl];
  const int px0 = (bx - t0) * 32;
  const float* in = ((lvl==1)?f1:(lvl==2)?f2:f3) + (size_t)bc * ED * HW + px0;
  float* outp = tfeat + cLOFF[lvl] + ((size_t)bc * HW + px0) * ED;
  const int t = threadIdx.x;
  const int npx = min(32, HW - px0);   // 32, or 16 on level-3 tail tile

#pragma unroll
  for (int j = 0; j < 8; ++j) {
    const int px = 4 * j;
    if (px < npx) {
      const float4 v = *(const float4*)(in + (size_t)t * HW + px);
      tile[(px+0)*LDST + t] = v.x;
      tile[(px+1)*LDST + t] = v.y;
      tile[(px+2)*LDST + t] = v.z;
      tile[(px+3)*LDST + t] = v.w;
    }
  }
  __syncthreads();
  const int wv = t >> 6, l = t & 63;
  for (int px = wv; px < npx; px += 4) {
    const float4 v = *(const float4*)&tile[px*LDST + 4*l];
    *(float4*)(outp + (size_t)px * ED + 4*l) = v;
  }
}

// ---------------- generic 2D transpose (w_fc only): in[R,C] -> out[C,R] ----
__global__ __launch_bounds__(256) void k_tr(const float* __restrict__ in,
                                            float* __restrict__ out, int R, int C)
{
  __shared__ float tile[32][33];
  const int r0 = blockIdx.y * 32, c0 = blockIdx.x * 32;
  const int tx = threadIdx.x, ty = threadIdx.y;  // (32,8)
#pragma unroll
  for (int kk = 0; kk < 4; ++kk) {
    const int r = r0 + ty + kk*8, c = c0 + tx;
    if (r < R && c < C) tile[ty + kk*8][tx] = in[(size_t)r*C + c];
  }
  __syncthreads();
#pragma unroll
  for (int kk = 0; kk < 4; ++kk) {
    const int c = c0 + ty + kk*8, r = r0 + tx;
    if (r < R && c < C) out[(size_t)c*R + r] = tile[tx][ty + kk*8];
  }
}

// ------- FC: wraw[1800,1344] = (inst+emb) @ wt + b_fc, wt = w_fc^T [256,1344] -------
__global__ __launch_bounds__(192) void k_fc(const float* __restrict__ inst,
    const float* __restrict__ emb, const float* __restrict__ wt,
    const float* __restrict__ b_fc, float* __restrict__ wraw)
{
  __shared__ float fsh[8][ED];
  const int a0 = blockIdx.x * 8;
  const int j  = blockIdx.y * 192 + threadIdx.x;
  const int t  = threadIdx.x;

  for (int i = t; i < 8 * ED; i += 192) {
    const int a = i >> 8, k = i & 255;
    const size_t idx = (size_t)(a0 + a) * ED + k;
    fsh[a][k] = inst[idx] + emb[idx];
  }
  __syncthreads();

  float acc[8] = {0.f,0.f,0.f,0.f,0.f,0.f,0.f,0.f};
  for (int k = 0; k < ED; k += 4) {
    float w0 = wt[(size_t)(k+0)*NJ + j];
    float w1 = wt[(size_t)(k+1)*NJ + j];
    float w2 = wt[(size_t)(k+2)*NJ + j];
    float w3 = wt[(size_t)(k+3)*NJ + j];
#pragma unroll
    for (int a = 0; a < 8; ++a)
      acc[a] += w0*fsh[a][k] + w1*fsh[a][k+1] + w2*fsh[a][k+2] + w3*fsh[a][k+3];
  }
  const float bj = b_fc[j];
#pragma unroll
  for (int a = 0; a < 8; ++a)
    wraw[(size_t)(a0+a)*NJ + j] = acc[a] + bj;
}

// ------- fused: softmax + projection + compacted hybrid gather ----
// CL=true: levels 1-3 from tfeat (channel-last), level 0 native.
// CL=false: all levels native (fallback if ws too small).
template<bool CL>
__global__ __launch_bounds__(256) void k_sample_h(
    const float* __restrict__ anchor, const float* __restrict__ proj,
    const float* __restrict__ wh, const float* __restrict__ wraw,
    const float* __restrict__ tfeat,
    const float* __restrict__ f0, const float* __restrict__ f1,
    const float* __restrict__ f2, const float* __restrict__ f3,
    float* __restrict__ fused)
{
  __shared__ float wsh[NJ];            // [g][e] layout (conflict-free)
  __shared__ float gridsh[NCAM][NP][2];
  __shared__ const float* cbase[NE];   // tap (0,0) base, channel 0
  __shared__ float4 cwt[NE];
  __shared__ int4   cmeta[NE];         // x=dx, y=dy, z=fl|(idx<<8), w=chstep
  __shared__ int wcnt[4];

  const int ba = blockIdx.x;
  const int b  = ba / A;
  const int t  = threadIdx.x;

  for (int j = t; j < NJ; j += 256)
    wsh[(j & 7) * NE + (j >> 3)] = wraw[(size_t)ba*NJ + j];

  if (t < NCAM*NP) {
    const int c = t / NP, p = t % NP;
    const float* an = anchor + (size_t)ba * 8;
    const float sx = expf(an[3]), sy = expf(an[4]), sz = expf(an[5]);
    const float sn = an[6], cs = an[7];
    const float kx = FIXS[p][0]*sx, ky = FIXS[p][1]*sy, kz = FIXS[p][2]*sz;
    const float px = cs*kx - sn*ky + an[0];
    const float py = sn*kx + cs*ky + an[1];
    const float pz = kz + an[2];
    const float* P = proj + ((size_t)(b*NCAM + c))*16;
    const float X = P[0]*px + P[1]*py + P[2]*pz  + P[3];
    const float Y = P[4]*px + P[5]*py + P[6]*pz  + P[7];
    const float Z = P[8]*px + P[9]*py + P[10]*pz + P[11];
    const float zc  = fmaxf(Z, 1e-5f);
    const float whx = fmaxf(wh[(b*NCAM+c)*2+0], 1e-5f);
    const float why = fmaxf(wh[(b*NCAM+c)*2+1], 1e-5f);
    gridsh[c][p][0] = (X/zc/whx)*2.f - 1.f;
    gridsh[c][p][1] = (Y/zc/why)*2.f - 1.f;
  }
  __syncthreads();

  bool valid = false;
  int fl = 0, dx = 0, dy = 0, chstep = 0;
  float wx1 = 0.f, wy1 = 0.f;
  const float* bptr = nullptr;
  if (t < NE) {
    const int c = t / (NL*NP); const int r = t % (NL*NP);
    const int l = r / NP, p = r % NP;
    const int Wl = cW[l], Hl = cH[l], HWl = cHW[l];
    const float gx = (gridsh[c][p][0] + 1.f) * (Wl * 0.5f) - 0.5f;
    const float gy = (gridsh[c][p][1] + 1.f) * (Hl * 0.5f) - 0.5f;
    const float x0f = floorf(gx), y0f = floorf(gy);
    const bool vx0 = (x0f >=  0.f) & (x0f <= (float)(Wl-1));
    const bool vx1 = (x0f >= -1.f) & (x0f <= (float)(Wl-2));
    const bool vy0 = (y0f >=  0.f) & (y0f <= (float)(Hl-1));
    const bool vy1 = (y0f >= -1.f) & (y0f <= (float)(Hl-2));
    fl = ((vx0&&vy0)?1:0) | ((vx1&&vy0)?2:0) | ((vx0&&vy1)?4:0) | ((vx1&&vy1)?8:0);
    if (fl) {
      wx1 = gx - x0f; wy1 = gy - y0f;
      const int x0 = (int)x0f, y0 = (int)y0f;
      if (CL && l >= 1) {
        bptr = tfeat + cLOFF[l]
             + ((size_t)(b*NCAM + c) * HWl + (long long)(y0*Wl + x0)) * ED;
        chstep = 1; dx = ED; dy = Wl * ED;
      } else {
        const float* fp = (l==0)?f0:(l==1)?f1:(l==2)?f2:f3;
        bptr = fp + (size_t)(b*NCAM + c) * ED * HWl + (long long)(y0*Wl + x0);
        chstep = HWl; dx = 1; dy = Wl;
      }
      valid = true;
    }
  }

  const unsigned long long mask = __ballot(valid);
  const int lane = t & 63, wv = t >> 6;
  if (lane == 0) wcnt[wv] = __popcll(mask);
  __syncthreads();
  int off = 0, nv = 0;
#pragma unroll
  for (int i = 0; i < 4; ++i) { if (i < wv) off += wcnt[i]; nv += wcnt[i]; }
  if (valid) {
    const int pos = off + __popcll(mask & ((1ull << lane) - 1ull));
    cbase[pos] = bptr;
    cwt[pos]   = make_float4((1.f-wx1)*(1.f-wy1), wx1*(1.f-wy1),
                             (1.f-wx1)*wy1,       wx1*wy1);
    cmeta[pos] = make_int4(dx, dy, fl | (t << 8), chstep);
  }

  // group softmax: 8 groups x 32 lanes, contiguous-e layout
  {
    const int g = t >> 5, ln = t & 31;
    float* wg = wsh + g * NE;
    float m = -3.4e38f;
    for (int i = ln; i < NE; i += 32) m = fmaxf(m, wg[i]);
#pragma unroll
    for (int mk = 16; mk >= 1; mk >>= 1) m = fmaxf(m, __shfl_xor(m, mk));
    float s = 0.f;
    for (int i = ln; i < NE; i += 32) {
      const float e = expf(wg[i] - m);
      wg[i] = e;
      s += e;
    }
#pragma unroll
    for (int mk = 16; mk >= 1; mk >>= 1) s += __shfl_xor(s, mk);
    const float inv = 1.f / s;
    for (int i = ln; i < NE; i += 32) wg[i] *= inv;
  }
  __syncthreads();

  float acc = 0.f;
  const int g = t >> 5;
  for (int i = 0; i < nv; ++i) {
    const int4 m = cmeta[i];
    const float* pb = cbase[i] + (size_t)t * m.w;
    const float4 w4 = cwt[i];
    const float aw = wsh[g*NE + (m.z >> 8)];
    const int f = m.z & 255;
    float sv = 0.f;
    if (f == 15) {
      sv = w4.x*pb[0] + w4.y*pb[m.x] + w4.z*pb[m.y] + w4.w*pb[m.x+m.y];
    } else {
      if (f & 1) sv += w4.x*pb[0];
      if (f & 2) sv += w4.y*pb[m.x];
      if (f & 4) sv += w4.z*pb[m.y];
      if (f & 8) sv += w4.w*pb[m.x+m.y];
    }
    acc += aw * sv;
  }
  fused[(size_t)ba*ED + t] = acc;
}

// ---------------- out = fused @ w_out^T + b_out ----------------
__global__ __launch_bounds__(256) void k_out(const float* __restrict__ fused,
    const float* __restrict__ w_out, const float* __restrict__ b_out,
    float* __restrict__ out)
{
  __shared__ float fsh[8][ED];
  const int a0 = blockIdx.x * 8;
  const int t = threadIdx.x;
#pragma unroll
  for (int k = 0; k < 8; ++k) fsh[k][t] = fused[(size_t)(a0+k)*ED + t];
  __syncthreads();
  float acc[8] = {0.f,0.f,0.f,0.f,0.f,0.f,0.f,0.f};
  for (int i = 0; i < ED; i += 4) {
    const float4 w4 = *(const float4*)&w_out[(size_t)t*ED + i];
#pragma unroll
    for (int k = 0; k < 8; ++k) {
      const float4 fv = *(const float4*)&fsh[k][i];
      acc[k] += w4.x*fv.x + w4.y*fv.y + w4.z*fv.z + w4.w*fv.w;
    }
  }
  const float bo = b_out[t];
#pragma unroll
  for (int k = 0; k < 8; ++k) out[(size_t)(a0+k)*ED + t] = acc[k] + bo;
}

extern "C" void kernel_launch(void* const* d_in, const int* in_sizes, int n_in,
                              void* d_out, int out_size, void* d_ws, size_t ws_size,
                              hipStream_t stream) {
  const float* inst   = (const float*)d_in[0];
  const float* anchor = (const float*)d_in[1];
  const float* emb    = (const float*)d_in[2];
  const float* f0 = (const float*)d_in[3];
  const float* f1 = (const float*)d_in[4];
  const float* f2 = (const float*)d_in[5];
  const float* f3 = (const float*)d_in[6];
  const float* proj  = (const float*)d_in[7];
  const float* wh    = (const float*)d_in[8];
  const float* w_fc  = (const float*)d_in[9];
  const float* b_fc  = (const float*)d_in[10];
  const float* w_out = (const float*)d_in[11];
  const float* b_out = (const float*)d_in[12];
  float* out = (float*)d_out;
  float* ws  = (float*)d_ws;

  const size_t TFEAT = 11354112ULL;   // levels 1-3 channel-last, floats
  const size_t WRAW  = (size_t)NBA * NJ;
  const size_t FUSED = (size_t)NBA * ED;
  const size_t WT    = (size_t)ED * NJ;
  const bool tr = ws_size >= (TFEAT + WRAW + FUSED + WT) * sizeof(float);

  float* tfeat  = ws;
  float* wraw   = tr ? (ws + TFEAT) : ws;
  float* fusedp = wraw + WRAW;
  float* wt     = fusedp + FUSED;

  // w_fc [1344,256] -> wt [256,1344]
  k_tr<<<dim3(ED/32, NJ/32, 1), dim3(32,8), 0, stream>>>(w_fc, wt, NJ, ED);

  if (tr)
    k_tr_cl<<<dim3(116, B*NCAM), 256, 0, stream>>>(f1, f2, f3, tfeat);

  k_fc<<<dim3(NBA / 8, 7), 192, 0, stream>>>(inst, emb, wt, b_fc, wraw);

  if (tr)
    k_sample_h<true><<<NBA, 256, 0, stream>>>(anchor, proj, wh, wraw, tfeat,
                                              f0, f1, f2, f3, fusedp);
  else
    k_sample_h<false><<<NBA, 256, 0, stream>>>(anchor, proj, wh, wraw, tfeat,
                                               f0, f1, f2, f3, fusedp);

  k_out<<<NBA / 8, 256, 0, stream>>>(fusedp, w_out, b_out, out);
}

// Round 6
// 365.384 us; speedup vs baseline: 1.1628x; 1.0422x over previous
//
#include <hip/hip_runtime.h>
#include <math.h>

constexpr int B = 2, A = 900, ED = 256, NG = 8, NCAM = 6, NL = 4, NP = 7;
constexpr int NJ = NG * NCAM * NL * NP;   // 1344
constexpr int NBA = B * A;                // 1800
constexpr int NE = NCAM * NL * NP;        // 168 point-level entries
constexpr int LDST = 260;                 // LDS row stride (16B aligned)
constexpr int SPLIT = 2;                  // entry-loop split across blocks
constexpr int EHALF = NE / SPLIT;         // 84

__constant__ float FIXS[NP][3] = {
  {0.f,0.f,0.f},{0.45f,0.f,0.f},{-0.45f,0.f,0.f},
  {0.f,0.45f,0.f},{0.f,-0.45f,0.f},{0.f,0.f,0.45f},{0.f,0.f,-0.45f}};

__constant__ int cH[NL]  = {64,32,16,8};
__constant__ int cW[NL]  = {176,88,44,22};
__constant__ int cHW[NL] = {11264,2816,704,176};
// float offsets of levels 1..3 inside tfeat (level 0 stays native)
__constant__ long long cLOFF[NL] = {0LL, 0LL, 8650752LL, 10813440LL};

// ---- channel-last transpose, levels 1-3 only ----
__global__ __launch_bounds__(256) void k_tr_cl(
    const float* __restrict__ f1, const float* __restrict__ f2,
    const float* __restrict__ f3, float* __restrict__ tfeat)
{
  __shared__ float tile[32 * LDST];
  const int bc = blockIdx.y;
  const int bx = blockIdx.x;
  int lvl, t0;
  if      (bx < 88)  { lvl = 1; t0 = 0; }
  else if (bx < 110) { lvl = 2; t0 = 88; }
  else               { lvl = 3; t0 = 110; }
  const int HW  = cHW[lvl];
  const int px0 = (bx - t0) * 32;
  const float* in = ((lvl==1)?f1:(lvl==2)?f2:f3) + (size_t)bc * ED * HW + px0;
  float* outp = tfeat + cLOFF[lvl] + ((size_t)bc * HW + px0) * ED;
  const int t = threadIdx.x;
  const int npx = min(32, HW - px0);

#pragma unroll
  for (int j = 0; j < 8; ++j) {
    const int px = 4 * j;
    if (px < npx) {
      const float4 v = *(const float4*)(in + (size_t)t * HW + px);
      tile[(px+0)*LDST + t] = v.x;
      tile[(px+1)*LDST + t] = v.y;
      tile[(px+2)*LDST + t] = v.z;
      tile[(px+3)*LDST + t] = v.w;
    }
  }
  __syncthreads();
  const int wv = t >> 6, l = t & 63;
  for (int px = wv; px < npx; px += 4) {
    const float4 v = *(const float4*)&tile[px*LDST + 4*l];
    *(float4*)(outp + (size_t)px * ED + 4*l) = v;
  }
}

// ---------------- generic 2D transpose (w_fc only): in[R,C] -> out[C,R] ----
__global__ __launch_bounds__(256) void k_tr(const float* __restrict__ in,
                                            float* __restrict__ out, int R, int C)
{
  __shared__ float tile[32][33];
  const int r0 = blockIdx.y * 32, c0 = blockIdx.x * 32;
  const int tx = threadIdx.x, ty = threadIdx.y;  // (32,8)
#pragma unroll
  for (int kk = 0; kk < 4; ++kk) {
    const int r = r0 + ty + kk*8, c = c0 + tx;
    if (r < R && c < C) tile[ty + kk*8][tx] = in[(size_t)r*C + c];
  }
  __syncthreads();
#pragma unroll
  for (int kk = 0; kk < 4; ++kk) {
    const int c = c0 + ty + kk*8, r = r0 + tx;
    if (r < R && c < C) out[(size_t)c*R + r] = tile[tx][ty + kk*8];
  }
}

// ------- FC: wraw[1800,1344] = (inst+emb) @ wt + b_fc, wt = w_fc^T [256,1344] -------
__global__ __launch_bounds__(192) void k_fc(const float* __restrict__ inst,
    const float* __restrict__ emb, const float* __restrict__ wt,
    const float* __restrict__ b_fc, float* __restrict__ wraw)
{
  __shared__ float fsh[8][ED];
  const int a0 = blockIdx.x * 8;
  const int j  = blockIdx.y * 192 + threadIdx.x;
  const int t  = threadIdx.x;

  for (int i = t; i < 8 * ED; i += 192) {
    const int a = i >> 8, k = i & 255;
    const size_t idx = (size_t)(a0 + a) * ED + k;
    fsh[a][k] = inst[idx] + emb[idx];
  }
  __syncthreads();

  float acc[8] = {0.f,0.f,0.f,0.f,0.f,0.f,0.f,0.f};
  for (int k = 0; k < ED; k += 4) {
    float w0 = wt[(size_t)(k+0)*NJ + j];
    float w1 = wt[(size_t)(k+1)*NJ + j];
    float w2 = wt[(size_t)(k+2)*NJ + j];
    float w3 = wt[(size_t)(k+3)*NJ + j];
#pragma unroll
    for (int a = 0; a < 8; ++a)
      acc[a] += w0*fsh[a][k] + w1*fsh[a][k+1] + w2*fsh[a][k+2] + w3*fsh[a][k+3];
  }
  const float bj = b_fc[j];
#pragma unroll
  for (int a = 0; a < 8; ++a)
    wraw[(size_t)(a0+a)*NJ + j] = acc[a] + bj;
}

// ------- fused: softmax + projection + branchless compacted hybrid gather ----
// grid (NBA, SPLIT): block y handles entries [y*EHALF, (y+1)*EHALF), writes
// partial sums to fused[y]. CL=true: levels>=1 channel-last from tfeat.
template<bool CL>
__global__ __launch_bounds__(256) void k_sample_h(
    const float* __restrict__ anchor, const float* __restrict__ proj,
    const float* __restrict__ wh, const float* __restrict__ wraw,
    const float* __restrict__ tfeat,
    const float* __restrict__ f0, const float* __restrict__ f1,
    const float* __restrict__ f2, const float* __restrict__ f3,
    float* __restrict__ fused)
{
  __shared__ float wsh[NJ];              // [g][e] layout (conflict-free)
  __shared__ float gridsh[NCAM][NP][2];
  __shared__ const float* cptr[EHALF][4]; // 4 pre-clamped tap pointers (ch 0)
  __shared__ float4 cwt[EHALF];           // validity-masked bilinear weights
  __shared__ int2   cmeta[EHALF];         // x=chstep, y=entry idx
  __shared__ int wcnt[4];

  const int ba   = blockIdx.x;
  const int half = blockIdx.y;
  const int b    = ba / A;
  const int t    = threadIdx.x;

  for (int j = t; j < NJ; j += 256)
    wsh[(j & 7) * NE + (j >> 3)] = wraw[(size_t)ba*NJ + j];

  if (t < NCAM*NP) {
    const int c = t / NP, p = t % NP;
    const float* an = anchor + (size_t)ba * 8;
    const float sx = expf(an[3]), sy = expf(an[4]), sz = expf(an[5]);
    const float sn = an[6], cs = an[7];
    const float kx = FIXS[p][0]*sx, ky = FIXS[p][1]*sy, kz = FIXS[p][2]*sz;
    const float px = cs*kx - sn*ky + an[0];
    const float py = sn*kx + cs*ky + an[1];
    const float pz = kz + an[2];
    const float* P = proj + ((size_t)(b*NCAM + c))*16;
    const float X = P[0]*px + P[1]*py + P[2]*pz  + P[3];
    const float Y = P[4]*px + P[5]*py + P[6]*pz  + P[7];
    const float Z = P[8]*px + P[9]*py + P[10]*pz + P[11];
    const float zc  = fmaxf(Z, 1e-5f);
    const float whx = fmaxf(wh[(b*NCAM+c)*2+0], 1e-5f);
    const float why = fmaxf(wh[(b*NCAM+c)*2+1], 1e-5f);
    gridsh[c][p][0] = (X/zc/whx)*2.f - 1.f;
    gridsh[c][p][1] = (Y/zc/why)*2.f - 1.f;
  }
  __syncthreads();

  // entries for this block: e = half*EHALF + (t if t < EHALF)
  bool valid = false;
  int chstep = 0;
  float4 w4 = make_float4(0.f,0.f,0.f,0.f);
  const float *p00=nullptr, *p10=nullptr, *p01=nullptr, *p11=nullptr;
  const int e = half * EHALF + t;
  if (t < EHALF) {
    const int c = e / (NL*NP); const int r = e % (NL*NP);
    const int l = r / NP, p = r % NP;
    const int Wl = cW[l], Hl = cH[l], HWl = cHW[l];
    const float gx = (gridsh[c][p][0] + 1.f) * (Wl * 0.5f) - 0.5f;
    const float gy = (gridsh[c][p][1] + 1.f) * (Hl * 0.5f) - 0.5f;
    const float x0f = floorf(gx), y0f = floorf(gy);
    const bool vx0 = (x0f >=  0.f) & (x0f <= (float)(Wl-1));
    const bool vx1 = (x0f >= -1.f) & (x0f <= (float)(Wl-2));
    const bool vy0 = (y0f >=  0.f) & (y0f <= (float)(Hl-1));
    const bool vy1 = (y0f >= -1.f) & (y0f <= (float)(Hl-2));
    if (vx0|vx1|vy0|vy1) {
      const float wx1 = gx - x0f, wy1 = gy - y0f;
      // clamp both tap coords into the image; invalid taps get weight 0
      const int x0 = (int)fmaxf(fminf(x0f,        (float)(Wl-1)), 0.f);
      const int x1 = (int)fmaxf(fminf(x0f + 1.f,  (float)(Wl-1)), 0.f);
      const int y0 = (int)fmaxf(fminf(y0f,        (float)(Hl-1)), 0.f);
      const int y1 = (int)fmaxf(fminf(y0f + 1.f,  (float)(Hl-1)), 0.f);
      w4 = make_float4((1.f-wx1)*(1.f-wy1)*(vx0&&vy0),
                       wx1*(1.f-wy1)*(vx1&&vy0),
                       (1.f-wx1)*wy1*(vx0&&vy1),
                       wx1*wy1*(vx1&&vy1));
      if (w4.x != 0.f || w4.y != 0.f || w4.z != 0.f || w4.w != 0.f) {
        const float* base;
        int estep;  // element stride for one pixel step
        if (CL && l >= 1) {
          base = tfeat + cLOFF[l] + (size_t)(b*NCAM + c) * HWl * ED;
          estep = ED; chstep = 1;
        } else {
          const float* fp = (l==0)?f0:(l==1)?f1:(l==2)?f2:f3;
          base = fp + (size_t)(b*NCAM + c) * ED * HWl;
          estep = 1; chstep = HWl;
        }
        p00 = base + (size_t)(y0*Wl + x0) * estep;
        p10 = base + (size_t)(y0*Wl + x1) * estep;
        p01 = base + (size_t)(y1*Wl + x0) * estep;
        p11 = base + (size_t)(y1*Wl + x1) * estep;
        valid = true;
      }
    }
  }

  const unsigned long long mask = __ballot(valid);
  const int lane = t & 63, wv = t >> 6;
  if (lane == 0) wcnt[wv] = __popcll(mask);
  __syncthreads();
  int off = 0, nv = 0;
#pragma unroll
  for (int i = 0; i < 4; ++i) { if (i < wv) off += wcnt[i]; nv += wcnt[i]; }
  if (valid) {
    const int pos = off + __popcll(mask & ((1ull << lane) - 1ull));
    cptr[pos][0] = p00; cptr[pos][1] = p10; cptr[pos][2] = p01; cptr[pos][3] = p11;
    cwt[pos]   = w4;
    cmeta[pos] = make_int2(chstep, e);
  }

  // group softmax over ALL entries (needed for correct normalization)
  {
    const int g = t >> 5, ln = t & 31;
    float* wg = wsh + g * NE;
    float m = -3.4e38f;
    for (int i = ln; i < NE; i += 32) m = fmaxf(m, wg[i]);
#pragma unroll
    for (int mk = 16; mk >= 1; mk >>= 1) m = fmaxf(m, __shfl_xor(m, mk));
    float s = 0.f;
    for (int i = ln; i < NE; i += 32) {
      const float ev = expf(wg[i] - m);
      wg[i] = ev;
      s += ev;
    }
#pragma unroll
    for (int mk = 16; mk >= 1; mk >>= 1) s += __shfl_xor(s, mk);
    const float inv = 1.f / s;
    for (int i = ln; i < NE; i += 32) wg[i] *= inv;
  }
  __syncthreads();

  float acc = 0.f;
  const int g = t >> 5;
#pragma unroll 4
  for (int i = 0; i < nv; ++i) {
    const int2 m = cmeta[i];
    const size_t toff = (size_t)t * m.x;
    const float4 w = cwt[i];
    const float aw = wsh[g*NE + m.y];
    const float v00 = cptr[i][0][toff];
    const float v10 = cptr[i][1][toff];
    const float v01 = cptr[i][2][toff];
    const float v11 = cptr[i][3][toff];
    acc += aw * (w.x*v00 + w.y*v10 + w.z*v01 + w.w*v11);
  }
  fused[((size_t)half * NBA + ba) * ED + t] = acc;
}

// ---------------- out = (fused0+fused1) @ w_out^T + b_out ----------------
__global__ __launch_bounds__(256) void k_out(const float* __restrict__ fused,
    const float* __restrict__ w_out, const float* __restrict__ b_out,
    float* __restrict__ out)
{
  __shared__ float fsh[8][ED];
  const int a0 = blockIdx.x * 8;
  const int t = threadIdx.x;
#pragma unroll
  for (int k = 0; k < 8; ++k)
    fsh[k][t] = fused[(size_t)(a0+k)*ED + t]
              + fused[(size_t)NBA*ED + (size_t)(a0+k)*ED + t];
  __syncthreads();
  float acc[8] = {0.f,0.f,0.f,0.f,0.f,0.f,0.f,0.f};
  for (int i = 0; i < ED; i += 4) {
    const float4 w4 = *(const float4*)&w_out[(size_t)t*ED + i];
#pragma unroll
    for (int k = 0; k < 8; ++k) {
      const float4 fv = *(const float4*)&fsh[k][i];
      acc[k] += w4.x*fv.x + w4.y*fv.y + w4.z*fv.z + w4.w*fv.w;
    }
  }
  const float bo = b_out[t];
#pragma unroll
  for (int k = 0; k < 8; ++k) out[(size_t)(a0+k)*ED + t] = acc[k] + bo;
}

extern "C" void kernel_launch(void* const* d_in, const int* in_sizes, int n_in,
                              void* d_out, int out_size, void* d_ws, size_t ws_size,
                              hipStream_t stream) {
  const float* inst   = (const float*)d_in[0];
  const float* anchor = (const float*)d_in[1];
  const float* emb    = (const float*)d_in[2];
  const float* f0 = (const float*)d_in[3];
  const float* f1 = (const float*)d_in[4];
  const float* f2 = (const float*)d_in[5];
  const float* f3 = (const float*)d_in[6];
  const float* proj  = (const float*)d_in[7];
  const float* wh    = (const float*)d_in[8];
  const float* w_fc  = (const float*)d_in[9];
  const float* b_fc  = (const float*)d_in[10];
  const float* w_out = (const float*)d_in[11];
  const float* b_out = (const float*)d_in[12];
  float* out = (float*)d_out;
  float* ws  = (float*)d_ws;

  const size_t TFEAT = 11354112ULL;   // levels 1-3 channel-last, floats
  const size_t WRAW  = (size_t)NBA * NJ;
  const size_t FUSED = (size_t)SPLIT * NBA * ED;
  const size_t WT    = (size_t)ED * NJ;
  const bool tr = ws_size >= (TFEAT + WRAW + FUSED + WT) * sizeof(float);

  float* tfeat  = ws;
  float* wraw   = tr ? (ws + TFEAT) : ws;
  float* fusedp = wraw + WRAW;
  float* wt     = fusedp + FUSED;

  // w_fc [1344,256] -> wt [256,1344]
  k_tr<<<dim3(ED/32, NJ/32, 1), dim3(32,8), 0, stream>>>(w_fc, wt, NJ, ED);

  if (tr)
    k_tr_cl<<<dim3(116, B*NCAM), 256, 0, stream>>>(f1, f2, f3, tfeat);

  k_fc<<<dim3(NBA / 8, 7), 192, 0, stream>>>(inst, emb, wt, b_fc, wraw);

  if (tr)
    k_sample_h<true><<<dim3(NBA, SPLIT), 256, 0, stream>>>(anchor, proj, wh,
        wraw, tfeat, f0, f1, f2, f3, fusedp);
  else
    k_sample_h<false><<<dim3(NBA, SPLIT), 256, 0, stream>>>(anchor, proj, wh,
        wraw, tfeat, f0, f1, f2, f3, fusedp);

  k_out<<<NBA / 8, 256, 0, stream>>>(fusedp, w_out, b_out, out);
}